// Round 9
// baseline (252.366 us; speedup 1.0000x reference)
//
#include <hip/hip_runtime.h>

#define NB 64
#define NN 100
#define DL 32
#define BN (NB * NN)  // 6400

typedef _Float16 f16x8 __attribute__((ext_vector_type(8)));
typedef float f32x4 __attribute__((ext_vector_type(4)));

static __device__ __forceinline__ float lrelu(float x) { return fmaxf(x, 0.1f * x); }

// Fused prep: h = x@lin_w+lin_b (f32), Uh/Vh f16 for step 0, W1 B-fragment swizzle
// (f16) + dist-row wdh for both steps.
__global__ __launch_bounds__(256) void k_pre(
    const float* __restrict__ x, const float* __restrict__ lw, const float* __restrict__ lb,
    const float* __restrict__ ew0a, const float* __restrict__ eb0a,
    const float* __restrict__ ew0b,
    const float* __restrict__ w1a, const float* __restrict__ w1b,
    float* __restrict__ h, _Float16* __restrict__ Uh, _Float16* __restrict__ Vh,
    _Float16* __restrict__ PW) {
    int blk = blockIdx.x;
    int t = threadIdx.x;
    if (blk >= 1600) {  // PW[step][kt][hf][lane][jj] + wdh[step][64] at PW+8192
        int step = blk - 1600;
        const float* w1 = step ? w1b : w1a;
        const float* ew0 = step ? ew0b : ew0a;
        _Float16* dst = PW + step * 4096;
#pragma unroll
        for (int u = 0; u < 16; ++u) {
            int idx = t * 16 + u;
            int jj = idx & 7, lane = (idx >> 3) & 63, hf = (idx >> 9) & 1, kt = idx >> 10;
            int c = hf * 32 + (lane >> 4) * 8 + jj;
            int k = kt * 16 + (lane & 15);
            dst[idx] = (_Float16)w1[c * 64 + k];
        }
        if (t < 64) PW[8192 + step * 64 + t] = (_Float16)ew0[64 * 64 + t];
        return;
    }
    __shared__ float xs[DL];
    __shared__ float hs[4][DL];
    int row0 = blk * 4;
    int b = row0 / NN;  // 4-row group never crosses a batch boundary (100 % 4 == 0)
    if (t < DL) xs[t] = x[b * DL + t];
    __syncthreads();
    if (t < 128) {
        int ni = t >> 5, c = t & 31;
        int n = (row0 + ni) % NN;
        float s = lb[n * DL + c];
#pragma unroll
        for (int cc = 0; cc < DL; ++cc) s += xs[cc] * lw[cc * 3200 + n * DL + c];
        hs[ni][c] = s;
        h[(row0 + ni) * DL + c] = s;
    }
    __syncthreads();
#pragma unroll
    for (int r = 0; r < 2; ++r) {
        int o = r * 256 + t;  // 0..511 : 4 rows x (64 U + 64 V)
        int ni = o >> 7, kw = o & 127;
        int which = kw >> 6, k = kw & 63;
        const float* wp = ew0a + (which ? DL * 64 : 0) + k;
        float s = which ? 0.f : eb0a[k];
#pragma unroll
        for (int c = 0; c < DL; ++c) s += hs[ni][c] * wp[c * 64];
        (which ? Vh : Uh)[(row0 + ni) * 64 + k] = (_Float16)s;
    }
}

// Dense pairwise distances: thread = (i, j); grid 3200 x 256 (2 i per block).
// Fills full 112-wide pad rows (j>=100 clamped to 99) so k_edge never reads garbage.
__global__ __launch_bounds__(256) void k_dist(const float* __restrict__ h,
                                              float* __restrict__ dist) {
    int i = blockIdx.x * 2 + (threadIdx.x >> 7);
    int j = threadIdx.x & 127;
    if (j >= 112) return;
    int b = i / NN;
    int jc = j < NN ? j : NN - 1;
    const float4* hi4 = (const float4*)(h + i * DL);
    const float4* hj4 = (const float4*)(h + (b * NN + jc) * DL);
    float s = 1e-12f;
#pragma unroll
    for (int r = 0; r < 8; ++r) {
        float4 a = hi4[r], c = hj4[r];
        float d0 = a.x - c.x, d1 = a.y - c.y, d2 = a.z - c.z, d3 = a.w - c.w;
        s += d0 * d0 + d1 * d1 + d2 * d2 + d3 * d3;
    }
    dist[i * 112 + j] = sqrtf(s);
}

// Edge MLP + j-aggregation. Grid 6400 (block = node i), 4 waves, wave w = k-tile w.
// NO LDS, NO barriers: dist/U/V/B all from global (L1-broadcast), packed-f16 A-build
// in MFMA layout, in-wave shuffle reduce, 16-lane agg store.
__global__ __launch_bounds__(256) void k_edge(
    const float* __restrict__ dist, const _Float16* __restrict__ Uh,
    const _Float16* __restrict__ Vh, const _Float16* __restrict__ PW,
    const _Float16* __restrict__ wdh, const float* __restrict__ b1,
    float* __restrict__ agg) {
    const int i = blockIdx.x;
    const int b = i / NN;
    const int t = threadIdx.x;
    const int w = t >> 6, lane = t & 63, q = lane >> 4, kk = lane & 15;
    const int cb = q * 8;

    f16x8 u0 = *(const f16x8*)&Uh[i * 64 + cb];
    f16x8 u1 = *(const f16x8*)&Uh[i * 64 + 32 + cb];
    f16x8 wd0 = *(const f16x8*)&wdh[cb];
    f16x8 wd1 = *(const f16x8*)&wdh[32 + cb];
    f16x8 Bf0 = *(const f16x8*)&PW[((w * 2 + 0) * 64 + lane) * 8];
    f16x8 Bf1 = *(const f16x8*)&PW[((w * 2 + 1) * 64 + lane) * 8];
    float b1k = b1[w * 16 + kk];

    const float* dr = dist + i * 112;
    const _Float16* vb = Vh + (size_t)(b * NN) * 64;
    f32x4 sacc = {0.f, 0.f, 0.f, 0.f};

#pragma unroll
    for (int jt = 0; jt < 7; ++jt) {
        int j = jt * 16 + kk;  // A row m = lane&15
        int jc = (jt == 6) ? (j < NN ? j : NN - 1) : j;
        _Float16 dh = (_Float16)dr[j];
        f16x8 v0 = *(const f16x8*)&vb[jc * 64 + cb];
        f16x8 v1 = *(const f16x8*)&vb[jc * 64 + 32 + cb];
        f16x8 s0 = u0 + v0 + wd0 * dh;  // v_pk_add / v_pk_fma
        f16x8 s1 = u1 + v1 + wd1 * dh;
        f16x8 A0 = __builtin_elementwise_max(s0, s0 * (_Float16)0.1f);
        f16x8 A1 = __builtin_elementwise_max(s1, s1 * (_Float16)0.1f);
        f32x4 a = {0.f, 0.f, 0.f, 0.f};
        a = __builtin_amdgcn_mfma_f32_16x16x32_f16(A0, Bf0, a, 0, 0, 0);
        a = __builtin_amdgcn_mfma_f32_16x16x32_f16(A1, Bf1, a, 0, 0, 0);
#pragma unroll
        for (int r = 0; r < 4; ++r) {
            float vv = lrelu(a[r] + b1k);
            if (jt < 6) sacc[r] += vv;          // jr = jt*16+q*4+r <= 95 < 100: no mask
            else sacc[r] += (q == 0) ? vv : 0.f;  // jt=6: valid rows 96..99 <=> q==0
        }
    }

    float s = sacc[0] + sacc[1] + sacc[2] + sacc[3];
    s += __shfl_xor(s, 16);
    s += __shfl_xor(s, 32);
    if (q == 0) agg[i * 64 + w * 16 + kk] = s;
}

// Node MLP (2 layers) + next-step U/V (or final projection+tanh). 4 i per block.
template <int FINAL>
__global__ __launch_bounds__(256) void k_node(
    const float* __restrict__ h, const float* __restrict__ agg,
    const float* __restrict__ w0n, const float* __restrict__ b0n,
    const float* __restrict__ w1n, const float* __restrict__ b1n,
    const float* __restrict__ wA, const float* __restrict__ bA,
    float* __restrict__ hout, _Float16* __restrict__ Uo, _Float16* __restrict__ Vo,
    float* __restrict__ out) {
    __shared__ float t0s[4][64];
    __shared__ float hs2[4][DL];
    int t = threadIdx.x;
    int n0 = blockIdx.x * 4;
    {
        int k = t & 63, ni = t >> 6;
        const float* hr = h + (n0 + ni) * DL;
        const float* ar = agg + (n0 + ni) * 64;
        float s = b0n[k];
#pragma unroll 8
        for (int c = 0; c < DL; ++c) s += hr[c] * w0n[c * 64 + k];
#pragma unroll 8
        for (int c = 0; c < 64; ++c) s += ar[c] * w0n[(DL + c) * 64 + k];
        t0s[ni][k] = lrelu(s);
    }
    __syncthreads();
    if (t < 128) {
        int k = t & 31, ni = t >> 5;
        const float* tr = t0s[ni];
        float s = b1n[k];
#pragma unroll 8
        for (int c = 0; c < 64; ++c) s += tr[c] * w1n[c * DL + k];
        float hv = lrelu(s);
        hs2[ni][k] = hv;
        if (!FINAL) hout[(n0 + ni) * DL + k] = hv;
    }
    __syncthreads();
    if (FINAL) {
        if (t < 12) {
            int o = t % 3, ni = t / 3;
            float s = bA[o];
#pragma unroll
            for (int c = 0; c < DL; ++c) s += hs2[ni][c] * wA[c * 3 + o];
            out[(n0 + ni) * 3 + o] = tanhf(s);
        }
    } else {
#pragma unroll
        for (int rpt = 0; rpt < 2; ++rpt) {
            int o = rpt * 256 + t;  // 4 i x (64 U + 64 V)
            int ni = o >> 7, kw = o & 127;
            int which = kw >> 6, k = kw & 63;
            const float* wp = wA + (which ? DL * 64 : 0) + k;
            float s = which ? 0.f : bA[k];
#pragma unroll
            for (int c = 0; c < DL; ++c) s += hs2[ni][c] * wp[c * 64];
            (which ? Vo : Uo)[(n0 + ni) * 64 + k] = (_Float16)s;
        }
    }
}

extern "C" void kernel_launch(void* const* d_in, const int* in_sizes, int n_in,
                              void* d_out, int out_size, void* d_ws, size_t ws_size,
                              hipStream_t stream) {
    const float* x     = (const float*)d_in[0];
    const float* lin_w = (const float*)d_in[1];
    const float* lin_b = (const float*)d_in[2];
    const float* ew0[2] = {(const float*)d_in[3],  (const float*)d_in[11]};
    const float* eb0[2] = {(const float*)d_in[4],  (const float*)d_in[12]};
    const float* ew1[2] = {(const float*)d_in[5],  (const float*)d_in[13]};
    const float* eb1[2] = {(const float*)d_in[6],  (const float*)d_in[14]};
    const float* nw0[2] = {(const float*)d_in[7],  (const float*)d_in[15]};
    const float* nb0[2] = {(const float*)d_in[8],  (const float*)d_in[16]};
    const float* nw1[2] = {(const float*)d_in[9],  (const float*)d_in[17]};
    const float* nb1[2] = {(const float*)d_in[10], (const float*)d_in[18]};
    const float* ow = (const float*)d_in[19];
    const float* ob = (const float*)d_in[20];
    float* out = (float*)d_out;

    float* h    = (float*)d_ws;                   // 6400 x 32 f32
    float* h2   = h + 204800;                     // 6400 x 32 f32
    float* dist = h2 + 204800;                    // 6400 x 112 f32
    float* agg  = dist + 716800;                  // 6400 x 64 f32
    _Float16* Uh  = (_Float16*)(agg + 409600);    // 6400 x 64 f16
    _Float16* Vh  = Uh + 409600;
    _Float16* Uh2 = Vh + 409600;
    _Float16* Vh2 = Uh2 + 409600;
    _Float16* PW  = Vh2 + 409600;                 // 2x4096 B-frags + 2x64 wdh

    k_pre<<<1602, 256, 0, stream>>>(x, lin_w, lin_b, ew0[0], eb0[0], ew0[1],
                                    ew1[0], ew1[1], h, Uh, Vh, PW);
    k_dist<<<BN / 2, 256, 0, stream>>>(h, dist);
    k_edge<<<BN, 256, 0, stream>>>(dist, Uh, Vh, PW, PW + 8192, eb1[0], agg);
    k_node<0><<<BN / 4, 256, 0, stream>>>(h, agg, nw0[0], nb0[0], nw1[0], nb1[0],
                                          ew0[1], eb0[1], h2, Uh2, Vh2, nullptr);
    k_dist<<<BN / 2, 256, 0, stream>>>(h2, dist);
    k_edge<<<BN, 256, 0, stream>>>(dist, Uh2, Vh2, PW + 4096, PW + 8256, eb1[1], agg);
    k_node<1><<<BN / 4, 256, 0, stream>>>(h2, agg, nw0[1], nb0[1], nw1[1], nb1[1],
                                          ow, ob, nullptr, nullptr, nullptr, out);
}

// Round 10
// 206.580 us; speedup vs baseline: 1.2216x; 1.2216x over previous
//
#include <hip/hip_runtime.h>

#define NB 64
#define NN 100
#define DL 32
#define BN (NB * NN)  // 6400

typedef _Float16 f16x8 __attribute__((ext_vector_type(8)));
typedef float f32x4 __attribute__((ext_vector_type(4)));

static __device__ __forceinline__ float lrelu(float x) { return fmaxf(x, 0.1f * x); }

// Fused prep: h = x@lin_w+lin_b (f32), Uh/Vh f16 for step 0, W1 B-fragment swizzle
// (f16) + dist-row wdh for both steps.
__global__ __launch_bounds__(256) void k_pre(
    const float* __restrict__ x, const float* __restrict__ lw, const float* __restrict__ lb,
    const float* __restrict__ ew0a, const float* __restrict__ eb0a,
    const float* __restrict__ ew0b,
    const float* __restrict__ w1a, const float* __restrict__ w1b,
    float* __restrict__ h, _Float16* __restrict__ Uh, _Float16* __restrict__ Vh,
    _Float16* __restrict__ PW) {
    int blk = blockIdx.x;
    int t = threadIdx.x;
    if (blk >= 1600) {  // PW[step][kt][hf][lane][jj] + wdh[step][64] at PW+8192
        int step = blk - 1600;
        const float* w1 = step ? w1b : w1a;
        const float* ew0 = step ? ew0b : ew0a;
        _Float16* dst = PW + step * 4096;
#pragma unroll
        for (int u = 0; u < 16; ++u) {
            int idx = t * 16 + u;
            int jj = idx & 7, lane = (idx >> 3) & 63, hf = (idx >> 9) & 1, kt = idx >> 10;
            int c = hf * 32 + (lane >> 4) * 8 + jj;
            int k = kt * 16 + (lane & 15);
            dst[idx] = (_Float16)w1[c * 64 + k];
        }
        if (t < 64) PW[8192 + step * 64 + t] = (_Float16)ew0[64 * 64 + t];
        return;
    }
    __shared__ float xs[DL];
    __shared__ float hs[4][DL];
    int row0 = blk * 4;
    int b = row0 / NN;  // 4-row group never crosses a batch boundary (100 % 4 == 0)
    if (t < DL) xs[t] = x[b * DL + t];
    __syncthreads();
    if (t < 128) {
        int ni = t >> 5, c = t & 31;
        int n = (row0 + ni) % NN;
        float s = lb[n * DL + c];
#pragma unroll
        for (int cc = 0; cc < DL; ++cc) s += xs[cc] * lw[cc * 3200 + n * DL + c];
        hs[ni][c] = s;
        h[(row0 + ni) * DL + c] = s;
    }
    __syncthreads();
#pragma unroll
    for (int r = 0; r < 2; ++r) {
        int o = r * 256 + t;  // 0..511 : 4 rows x (64 U + 64 V)
        int ni = o >> 7, kw = o & 127;
        int which = kw >> 6, k = kw & 63;
        const float* wp = ew0a + (which ? DL * 64 : 0) + k;
        float s = which ? 0.f : eb0a[k];
#pragma unroll
        for (int c = 0; c < DL; ++c) s += hs[ni][c] * wp[c * 64];
        (which ? Vh : Uh)[(row0 + ni) * 64 + k] = (_Float16)s;
    }
}

// Dense pairwise distances: thread = (i, j); grid 3200 x 256 (2 i per block).
__global__ __launch_bounds__(256) void k_dist(const float* __restrict__ h,
                                              float* __restrict__ dist) {
    int i = blockIdx.x * 2 + (threadIdx.x >> 7);
    int j = threadIdx.x & 127;
    if (j >= 112) return;
    int b = i / NN;
    int jc = j < NN ? j : NN - 1;
    const float4* hi4 = (const float4*)(h + i * DL);
    const float4* hj4 = (const float4*)(h + (b * NN + jc) * DL);
    float s = 1e-12f;
#pragma unroll
    for (int r = 0; r < 8; ++r) {
        float4 a = hi4[r], c = hj4[r];
        float d0 = a.x - c.x, d1 = a.y - c.y, d2 = a.z - c.z, d3 = a.w - c.w;
        s += d0 * d0 + d1 * d1 + d2 * d2 + d3 * d3;
    }
    dist[i * 112 + j] = sqrtf(s);
}

// Edge MLP + j-aggregation. Grid 1600 x 256: wave = one node i, ALL 4 k-tiles.
// A-fragments built ONCE per i (R9 built them redundantly in all 4 waves), 8 MFMA
// per j-tile per wave, explicit 1-deep software pipeline on the V/dist loads.
// launch_bounds(256,4): 128-VGPR budget (R2-verified pattern; block=64 variants spilled).
__global__ __launch_bounds__(256, 4) void k_edge(
    const float* __restrict__ dist, const _Float16* __restrict__ Uh,
    const _Float16* __restrict__ Vh, const _Float16* __restrict__ PW,
    const _Float16* __restrict__ wdh, const float* __restrict__ b1,
    float* __restrict__ agg) {
    const int i = blockIdx.x * 4 + (threadIdx.x >> 6);
    const int b = i / NN;  // 4-group never crosses batch (100 % 4 == 0)
    const int lane = threadIdx.x & 63;
    const int q = lane >> 4, kk = lane & 15;
    const int cb = q * 8;

    f16x8 u0 = *(const f16x8*)&Uh[i * 64 + cb];
    f16x8 u1 = *(const f16x8*)&Uh[i * 64 + 32 + cb];
    f16x8 wd0 = *(const f16x8*)&wdh[cb];
    f16x8 wd1 = *(const f16x8*)&wdh[32 + cb];
    f16x8 Bf[4][2];
#pragma unroll
    for (int kt = 0; kt < 4; ++kt)
#pragma unroll
        for (int hf = 0; hf < 2; ++hf)
            Bf[kt][hf] = *(const f16x8*)&PW[((kt * 2 + hf) * 64 + lane) * 8];
    float b1k[4];
#pragma unroll
    for (int kt = 0; kt < 4; ++kt) b1k[kt] = b1[kt * 16 + kk];

    const float* dr = dist + i * 112;
    const _Float16* vb = Vh + (size_t)(b * NN) * 64;
    f32x4 sacc[4];
#pragma unroll
    for (int kt = 0; kt < 4; ++kt) sacc[kt] = (f32x4){0.f, 0.f, 0.f, 0.f};

    // pipeline prologue: tile 0 loads
    _Float16 dh = (_Float16)dr[kk];
    f16x8 v0 = *(const f16x8*)&vb[kk * 64 + cb];
    f16x8 v1 = *(const f16x8*)&vb[kk * 64 + 32 + cb];

#pragma unroll
    for (int jt = 0; jt < 7; ++jt) {
        // A-build from current tile's registers
        f16x8 s0 = u0 + v0 + wd0 * dh;  // v_pk_add / v_pk_fma
        f16x8 s1 = u1 + v1 + wd1 * dh;
        f16x8 A0 = __builtin_elementwise_max(s0, s0 * (_Float16)0.1f);
        f16x8 A1 = __builtin_elementwise_max(s1, s1 * (_Float16)0.1f);
        // prefetch next tile (independent addresses; overlaps the 8 MFMAs below)
        if (jt < 6) {
            int j = (jt + 1) * 16 + kk;
            int jc = j < NN ? j : NN - 1;  // only clamps when jt+1 == 6
            dh = (_Float16)dr[j];
            v0 = *(const f16x8*)&vb[jc * 64 + cb];
            v1 = *(const f16x8*)&vb[jc * 64 + 32 + cb];
        }
#pragma unroll
        for (int kt = 0; kt < 4; ++kt) {
            f32x4 a = {0.f, 0.f, 0.f, 0.f};
            a = __builtin_amdgcn_mfma_f32_16x16x32_f16(A0, Bf[kt][0], a, 0, 0, 0);
            a = __builtin_amdgcn_mfma_f32_16x16x32_f16(A1, Bf[kt][1], a, 0, 0, 0);
#pragma unroll
            for (int r = 0; r < 4; ++r) {
                float vv = lrelu(a[r] + b1k[kt]);
                if (jt < 6) sacc[kt][r] += vv;            // rows <= 95: no mask
                else sacc[kt][r] += (q == 0) ? vv : 0.f;  // rows 96..99 <=> q==0
            }
        }
    }

#pragma unroll
    for (int kt = 0; kt < 4; ++kt) {
        float s = sacc[kt][0] + sacc[kt][1] + sacc[kt][2] + sacc[kt][3];
        s += __shfl_xor(s, 16);
        s += __shfl_xor(s, 32);
        if (q == 0) agg[i * 64 + kt * 16 + kk] = s;
    }
}

// Node MLP (2 layers) + next-step U/V (or final projection+tanh). 4 i per block.
template <int FINAL>
__global__ __launch_bounds__(256) void k_node(
    const float* __restrict__ h, const float* __restrict__ agg,
    const float* __restrict__ w0n, const float* __restrict__ b0n,
    const float* __restrict__ w1n, const float* __restrict__ b1n,
    const float* __restrict__ wA, const float* __restrict__ bA,
    float* __restrict__ hout, _Float16* __restrict__ Uo, _Float16* __restrict__ Vo,
    float* __restrict__ out) {
    __shared__ float t0s[4][64];
    __shared__ float hs2[4][DL];
    int t = threadIdx.x;
    int n0 = blockIdx.x * 4;
    {
        int k = t & 63, ni = t >> 6;
        const float* hr = h + (n0 + ni) * DL;
        const float* ar = agg + (n0 + ni) * 64;
        float s = b0n[k];
#pragma unroll 8
        for (int c = 0; c < DL; ++c) s += hr[c] * w0n[c * 64 + k];
#pragma unroll 8
        for (int c = 0; c < 64; ++c) s += ar[c] * w0n[(DL + c) * 64 + k];
        t0s[ni][k] = lrelu(s);
    }
    __syncthreads();
    if (t < 128) {
        int k = t & 31, ni = t >> 5;
        const float* tr = t0s[ni];
        float s = b1n[k];
#pragma unroll 8
        for (int c = 0; c < 64; ++c) s += tr[c] * w1n[c * DL + k];
        float hv = lrelu(s);
        hs2[ni][k] = hv;
        if (!FINAL) hout[(n0 + ni) * DL + k] = hv;
    }
    __syncthreads();
    if (FINAL) {
        if (t < 12) {
            int o = t % 3, ni = t / 3;
            float s = bA[o];
#pragma unroll
            for (int c = 0; c < DL; ++c) s += hs2[ni][c] * wA[c * 3 + o];
            out[(n0 + ni) * 3 + o] = tanhf(s);
        }
    } else {
#pragma unroll
        for (int rpt = 0; rpt < 2; ++rpt) {
            int o = rpt * 256 + t;  // 4 i x (64 U + 64 V)
            int ni = o >> 7, kw = o & 127;
            int which = kw >> 6, k = kw & 63;
            const float* wp = wA + (which ? DL * 64 : 0) + k;
            float s = which ? 0.f : bA[k];
#pragma unroll
            for (int c = 0; c < DL; ++c) s += hs2[ni][c] * wp[c * 64];
            (which ? Vo : Uo)[(n0 + ni) * 64 + k] = (_Float16)s;
        }
    }
}

extern "C" void kernel_launch(void* const* d_in, const int* in_sizes, int n_in,
                              void* d_out, int out_size, void* d_ws, size_t ws_size,
                              hipStream_t stream) {
    const float* x     = (const float*)d_in[0];
    const float* lin_w = (const float*)d_in[1];
    const float* lin_b = (const float*)d_in[2];
    const float* ew0[2] = {(const float*)d_in[3],  (const float*)d_in[11]};
    const float* eb0[2] = {(const float*)d_in[4],  (const float*)d_in[12]};
    const float* ew1[2] = {(const float*)d_in[5],  (const float*)d_in[13]};
    const float* eb1[2] = {(const float*)d_in[6],  (const float*)d_in[14]};
    const float* nw0[2] = {(const float*)d_in[7],  (const float*)d_in[15]};
    const float* nb0[2] = {(const float*)d_in[8],  (const float*)d_in[16]};
    const float* nw1[2] = {(const float*)d_in[9],  (const float*)d_in[17]};
    const float* nb1[2] = {(const float*)d_in[10], (const float*)d_in[18]};
    const float* ow = (const float*)d_in[19];
    const float* ob = (const float*)d_in[20];
    float* out = (float*)d_out;

    float* h    = (float*)d_ws;                   // 6400 x 32 f32
    float* h2   = h + 204800;                     // 6400 x 32 f32
    float* dist = h2 + 204800;                    // 6400 x 112 f32
    float* agg  = dist + 716800;                  // 6400 x 64 f32
    _Float16* Uh  = (_Float16*)(agg + 409600);    // 6400 x 64 f16
    _Float16* Vh  = Uh + 409600;
    _Float16* Uh2 = Vh + 409600;
    _Float16* Vh2 = Uh2 + 409600;
    _Float16* PW  = Vh2 + 409600;                 // 2x4096 B-frags + 2x64 wdh

    k_pre<<<1602, 256, 0, stream>>>(x, lin_w, lin_b, ew0[0], eb0[0], ew0[1],
                                    ew1[0], ew1[1], h, Uh, Vh, PW);
    k_dist<<<BN / 2, 256, 0, stream>>>(h, dist);
    k_edge<<<BN / 4, 256, 0, stream>>>(dist, Uh, Vh, PW, PW + 8192, eb1[0], agg);
    k_node<0><<<BN / 4, 256, 0, stream>>>(h, agg, nw0[0], nb0[0], nw1[0], nb1[0],
                                          ew0[1], eb0[1], h2, Uh2, Vh2, nullptr);
    k_dist<<<BN / 2, 256, 0, stream>>>(h2, dist);
    k_edge<<<BN / 4, 256, 0, stream>>>(dist, Uh2, Vh2, PW + 4096, PW + 8256, eb1[1], agg);
    k_node<1><<<BN / 4, 256, 0, stream>>>(h2, agg, nw0[1], nb0[1], nw1[1], nb1[1],
                                          ow, ob, nullptr, nullptr, nullptr, out);
}